// Round 6
// baseline (179.692 us; speedup 1.0000x reference)
//
#include <hip/hip_runtime.h>

#define BB 8
#define NN 8192
#define SS 2048
#define CC 64
#define NS 32
#define COUT 67        // 3 xyz + 64 feature channels
#define QT 4           // queries per block (one scan-wave each)
#define SLOTS (QT*NS)  // 128 (query,sample) slots per block
#define HSTR 33        // half-tile LDS stride: write free, transpose-read 2-way

// ---------------- Fused kernel: scan (wave-per-query) + gather --------------
// Phase 1: wave w ball-queries s0+w into LDS, with DOUBLE-BUFFERED point
// loads: chunk k+1's three dwordx4 loads issue before chunk k's ballot chain,
// so the early-exit branch never serializes load latency (was load(~220cy) ->
// ballot -> next load; now max(latency-overlap, VALU)). Bit-exact arithmetic.
// Phase 2: R5 gather (half-channel staging, 18.5 KB LDS, 6 blocks/CU).
__global__ __launch_bounds__(256, 6) void fused_kernel(
    const float* __restrict__ xyz,      // (B, N, 3)
    const float* __restrict__ new_xyz,  // (B, S, 3)
    const float* __restrict__ feat,     // (B, N, C)
    float* __restrict__ out)            // (B, 67, S, NS)
{
#pragma clang fp contract(off)
    __shared__ float fh[SLOTS * HSTR];   // 128*33*4B = 16.5 KB (half channels)
    __shared__ float xt[3 * SLOTS];      // 1.5 KB, [plane][slot]
    __shared__ int idx_sh[SLOTS];        // 0.5 KB

    const int t   = threadIdx.x;
    const int w   = t >> 6;              // wave 0..3
    const int ln  = t & 63;
    const int bid = blockIdx.x;          // 0..4095, b-fastest (XCD-affine)
    const int b     = bid & 7;
    const int sTile = bid >> 3;          // 0..511
    const int s0 = sTile * QT;

    // ================= Phase 1: ball-query scan (bit-exact) =================
    {
        const int s = s0 + w;
        const float R2 = 0.04f;          // strict '<' matches ref

        const float* ctr = new_xyz + ((size_t)b * SS + s) * 3;
        const float cx = ctr[0], cy = ctr[1], cz = ctr[2];
        const float* xb = xyz + (size_t)b * NN * 3;

        int* myidx = idx_sh + (w << 5);
        const unsigned long long lt = (1ull << ln) - 1ull;

        // preload chunk 0 (48B-aligned: (4*ln)*12 is a multiple of 48)
        const float4* p4 = (const float4*)(xb + (size_t)(ln << 2) * 3);
        float4 A  = p4[0];   // x0 y0 z0 x1
        float4 Bv = p4[1];   // y1 z1 x2 y2
        float4 Cv = p4[2];   // z2 x3 y3 z3

        int total = 0;
        int firstIdx = -1;
        for (int j0 = 0; j0 < NN && total < NS; j0 += 256) {
            // ---- issue next chunk's loads BEFORE processing current ----
            float4 A2, B2, C2;
            const bool more = (j0 + 256) < NN;
            if (more) {
                const float4* pn =
                    (const float4*)(xb + (size_t)(j0 + 256 + (ln << 2)) * 3);
                A2 = pn[0]; B2 = pn[1]; C2 = pn[2];
            }

            float d2v[4];
            {
                const float dx = A.x - cx, dy = A.y - cy, dz = A.z - cz;
                float d2 = dx * dx; d2 = d2 + dy * dy; d2 = d2 + dz * dz;
                d2v[0] = d2;
            }
            {
                const float dx = A.w - cx, dy = Bv.x - cy, dz = Bv.y - cz;
                float d2 = dx * dx; d2 = d2 + dy * dy; d2 = d2 + dz * dz;
                d2v[1] = d2;
            }
            {
                const float dx = Bv.z - cx, dy = Bv.w - cy, dz = Cv.x - cz;
                float d2 = dx * dx; d2 = d2 + dy * dy; d2 = d2 + dz * dz;
                d2v[2] = d2;
            }
            {
                const float dx = Cv.y - cx, dy = Cv.z - cy, dz = Cv.w - cz;
                float d2 = dx * dx; d2 = d2 + dy * dy; d2 = d2 + dz * dz;
                d2v[3] = d2;
            }

            unsigned long long M[4];
#pragma unroll
            for (int u = 0; u < 4; ++u) M[u] = __ballot(d2v[u] < R2);

            if (firstIdx < 0) {
                int fmin = 0x7fffffff;
#pragma unroll
                for (int u = 0; u < 4; ++u)
                    if (M[u] != 0ull) {
                        const int j = j0 + (__builtin_ctzll(M[u]) << 2) + u;
                        fmin = (j < fmin) ? j : fmin;
                    }
                if (fmin != 0x7fffffff) firstIdx = fmin;
            }

            int below = 0;   // hits in earlier lanes (any u) -> smaller j
#pragma unroll
            for (int u = 0; u < 4; ++u) below += (int)__popcll(M[u] & lt);

            int own = 0;     // own hits with smaller u -> smaller j
#pragma unroll
            for (int u = 0; u < 4; ++u) {
                if (d2v[u] < R2) {
                    const int pos = total + below + own;
                    if (pos < NS) myidx[pos] = j0 + (ln << 2) + u;
                    ++own;
                }
            }
#pragma unroll
            for (int u = 0; u < 4; ++u) total += (int)__popcll(M[u]);

            A = A2; Bv = B2; Cv = C2;   // rotate double buffer
        }
        if (total < NS) {
            const int fill = (total > 0) ? firstIdx : 0;
            if (ln >= total && ln < NS) myidx[ln] = fill;
        }
    }
    __syncthreads();

    // ================= Phase 2: gather, half-channel staged =================
    // ---- xyz planes: one slot per thread (small, divergent but tiny) ----
    if (t < SLOTS) {
        const int r = idx_sh[t];
        const int q = t >> 5;
        const float* ctr = new_xyz + ((size_t)b * SS + s0 + q) * 3;
        const float* p   = xyz + ((size_t)b * NN + r) * 3;
        xt[0 * SLOTS + t] = p[0] - ctr[0];
        xt[1 * SLOTS + t] = p[1] - ctr[1];
        xt[2 * SLOTS + t] = p[2] - ctr[2];
    }

    const int c32 = ln & 31;             // channel within half
    const int sub = ln >> 5;             // which of 2 rows this lane covers
    const float* fb = feat + (size_t)b * NN * CC;
    const size_t plane = (size_t)SS * NS;
    float* ob = out + ((size_t)b * COUT * SS + s0) * NS;

    // ---- stage half 0: channels 0..31 for all 128 slots ----
    for (int i = 0; i < 16; i += 4) {
        float v[4];
        int   mm[4];
#pragma unroll
        for (int u = 0; u < 4; ++u) {
            const int m = (w << 5) + ((i + u) << 1) + sub;
            mm[u] = m;
            v[u]  = fb[(size_t)idx_sh[m] * CC + c32];
        }
#pragma unroll
        for (int u = 0; u < 4; ++u)
            fh[mm[u] * HSTR + c32] = v[u];             // 2 lanes/bank, free
    }
    __syncthreads();

    // ---- write-out planes 0..34: 70 tasks of one 256B wave-store ----
    for (int i = 0; i < 18; ++i) {
        const int tau = (i << 2) + w;
        if (tau < 70) {
            const int p  = tau >> 1;
            const int sl = ((tau & 1) << 6) + ln;
            const float val = (p < 3) ? xt[p * SLOTS + sl]
                                      : fh[sl * HSTR + (p - 3)];  // 2-way, free
            ob[(size_t)p * plane + sl] = val;
        }
    }
    __syncthreads();

    // ---- stage half 1: channels 32..63 ----
    for (int i = 0; i < 16; i += 4) {
        float v[4];
        int   mm[4];
#pragma unroll
        for (int u = 0; u < 4; ++u) {
            const int m = (w << 5) + ((i + u) << 1) + sub;
            mm[u] = m;
            v[u]  = fb[(size_t)idx_sh[m] * CC + 32 + c32];
        }
#pragma unroll
        for (int u = 0; u < 4; ++u)
            fh[mm[u] * HSTR + c32] = v[u];
    }
    __syncthreads();

    // ---- write-out planes 35..66: exactly 64 tasks ----
    for (int i = 0; i < 16; ++i) {
        const int tau = (i << 2) + w;
        const int pl  = tau >> 1;                       // 0..31
        const int sl  = ((tau & 1) << 6) + ln;
        ob[(size_t)(35 + pl) * plane + sl] = fh[sl * HSTR + pl];
    }
}

extern "C" void kernel_launch(void* const* d_in, const int* in_sizes, int n_in,
                              void* d_out, int out_size, void* d_ws, size_t ws_size,
                              hipStream_t stream) {
    const float* xyz     = (const float*)d_in[0];
    const float* new_xyz = (const float*)d_in[1];
    const float* feat    = (const float*)d_in[2];
    float* out = (float*)d_out;
    (void)d_ws; (void)ws_size;   // idx lives in LDS

    fused_kernel<<<dim3((BB * SS) / QT), dim3(256), 0, stream>>>(xyz, new_xyz, feat, out);
}